// Round 1
// 482.423 us; speedup vs baseline: 1.0131x; 1.0131x over previous
//
#include <hip/hip_runtime.h>
#include <math.h>

#define NUM_CLASSES 81

typedef float vfloat4 __attribute__((ext_vector_type(4)));

__device__ __forceinline__ float4 decode_clip(const float4 b, const float4 r,
                                              const float wmax, const float hmax)
{
    const float BBOX_XFORM_CLIP = 4.135166556742356f; // log(1000/16)
    const float w  = b.z - b.x + 1.0f;
    const float h  = b.w - b.y + 1.0f;
    const float cx = b.x + 0.5f * w;
    const float cy = b.y + 0.5f * h;
    const float dx = r.x * 0.1f;
    const float dy = r.y * 0.1f;
    const float dw = fminf(r.z * 0.2f, BBOX_XFORM_CLIP);
    const float dh = fminf(r.w * 0.2f, BBOX_XFORM_CLIP);
    const float px = dx * w + cx;
    const float py = dy * h + cy;
    const float pw = expf(dw) * w;
    const float ph = expf(dh) * h;
    const float x1 = fminf(fmaxf(px - 0.5f * pw, 0.0f), wmax);
    const float y1 = fminf(fmaxf(py - 0.5f * ph, 0.0f), hmax);
    const float x2 = fminf(fmaxf(px + 0.5f * pw - 1.0f, 0.0f), wmax);
    const float y2 = fminf(fmaxf(py + 0.5f * ph - 1.0f, 0.0f), hmax);
    return make_float4(x1, y1, x2, y2);
}

// ============================================================================
// Kernel 1: boxes — pure streaming write of the 81x-tiled decoded boxes.
// 64 rows/block, 256 threads. Decode into LDS (wave 0 only), one barrier,
// then 20 fully-unrolled contiguous nontemporal float4 stores per thread.
// Structurally a fill kernel (which hits 6.2 TB/s on this chip).
// ============================================================================
#define BROWS  64
#define BELEMS (BROWS * NUM_CLASSES)   // 5184 float4 outputs per block
#define BITERS (BELEMS / 256)          // 20 full iterations; tail = 64

__global__ __launch_bounds__(256) void boxes_kernel(
    const float4* __restrict__ box_reg4,
    const float4* __restrict__ prop4,
    const int* __restrict__ img_w_p,
    const int* __restrict__ img_h_p,
    float* __restrict__ out_boxes,
    int N)
{
    __shared__ float4 lds_box[BROWS];
    const int tid  = threadIdx.x;
    const int row0 = blockIdx.x * BROWS;
    if (row0 >= N) return;
    const int rows = min(BROWS, N - row0);

    if (tid < rows) {
        const int row = row0 + tid;
        const float wmax = (float)(*img_w_p) - 1.0f;
        const float hmax = (float)(*img_h_p) - 1.0f;
        lds_box[tid] = decode_clip(prop4[row], box_reg4[row], wmax, hmax);
    }
    __syncthreads();

    vfloat4* dst = (vfloat4*)out_boxes + (size_t)row0 * NUM_CLASSES;
    if (rows == BROWS) {
        #pragma unroll
        for (int i = 0; i < BITERS; ++i) {
            const int j = tid + i * 256;
            // j < 5184: magic div by 81, exact for j < 20971
            const int rloc = (int)(((unsigned)j * 12946u) >> 20);
            const float4 bx = lds_box[rloc];
            vfloat4 bv = { bx.x, bx.y, bx.z, bx.w };
            __builtin_nontemporal_store(bv, dst + j);
        }
        // tail: last 64 float4s of the block's 5184
        if (tid < (BELEMS - BITERS * 256)) {
            const int j = BITERS * 256 + tid;
            const int rloc = (int)(((unsigned)j * 12946u) >> 20);
            const float4 bx = lds_box[rloc];
            vfloat4 bv = { bx.x, bx.y, bx.z, bx.w };
            __builtin_nontemporal_store(bv, dst + j);
        }
    } else {
        const int elems = rows * NUM_CLASSES;
        for (int i = 0; i <= BITERS; ++i) {
            const int j = tid + i * 256;
            if (j < elems) {
                const int rloc = (int)(((unsigned)j * 12946u) >> 20);
                const float4 bx = lds_box[rloc];
                vfloat4 bv = { bx.x, bx.y, bx.z, bx.w };
                __builtin_nontemporal_store(bv, dst + j);
            }
        }
    }
}

// ============================================================================
// Kernel 2: softmax scores — identical to the proven fused path minus boxes.
// 16 rows/block, 256 threads; float4-coalesced LDS staging, 16 lanes/row
// shuffle softmax, float4 nontemporal writeback.
// ============================================================================
#define SROWS  16
#define SELEMS (SROWS * NUM_CLASSES)   // 1296 floats
#define SVECS  (SELEMS / 4)            // 324 float4s

__global__ __launch_bounds__(256) void scores_kernel(
    const float* __restrict__ logits,
    float* __restrict__ out_scores,
    int N)
{
    __shared__ vfloat4 lds4[SVECS];
    float* lds_val = (float*)lds4;
    const int tid  = threadIdx.x;
    const int row0 = blockIdx.x * SROWS;
    if (row0 >= N) return;
    const int rows = min(SROWS, N - row0);
    const bool full = (rows == SROWS);
    const int elems = rows * NUM_CLASSES;

    // ---------- stage logits ----------
    const float* lbase = logits + (size_t)row0 * NUM_CLASSES;
    if (full) {
        const vfloat4* lbase4 = (const vfloat4*)lbase;  // 1296*4B per block: 16B-aligned
        { int idx = tid;        lds4[idx] = lbase4[idx]; }
        { int idx = tid + 256;  if (idx < SVECS) lds4[idx] = lbase4[idx]; }
    } else {
        for (int i = 0; i < 6; ++i) {
            int e = tid + i * 256;
            if (e < elems) lds_val[e] = lbase[e];
        }
    }
    __syncthreads();

    // ---------- softmax: 16 lanes per row ----------
    const int sub = tid & 15;
    const int rl  = tid >> 4;
    if (rl < rows) {
        float* rowv = lds_val + rl * NUM_CLASSES;

        float v[6];
        float m = -INFINITY;
        #pragma unroll
        for (int i = 0; i < 6; ++i) {
            const int k = sub + i * 16;
            if (k < NUM_CLASSES) { v[i] = rowv[k]; m = fmaxf(m, v[i]); }
            else                 { v[i] = -INFINITY; }
        }
        #pragma unroll
        for (int off = 1; off <= 8; off <<= 1)
            m = fmaxf(m, __shfl_xor(m, off));

        float s = 0.0f;
        #pragma unroll
        for (int i = 0; i < 6; ++i) {
            const int k = sub + i * 16;
            if (k < NUM_CLASSES) { v[i] = __expf(v[i] - m); s += v[i]; }
        }
        #pragma unroll
        for (int off = 1; off <= 8; off <<= 1)
            s += __shfl_xor(s, off);

        const float inv = 1.0f / s;
        #pragma unroll
        for (int i = 0; i < 6; ++i) {
            const int k = sub + i * 16;
            if (k < NUM_CLASSES) rowv[k] = v[i] * inv;  // own slots only: no race
        }
    }
    __syncthreads();

    // ---------- writeback ----------
    float* sdst = out_scores + (size_t)row0 * NUM_CLASSES;
    if (full) {
        vfloat4* sdst4 = (vfloat4*)sdst;
        { int idx = tid;       __builtin_nontemporal_store(lds4[idx], sdst4 + idx); }
        { int idx = tid + 256; if (idx < SVECS)
                               __builtin_nontemporal_store(lds4[idx], sdst4 + idx); }
    } else {
        for (int i = 0; i < 6; ++i) {
            int e = tid + i * 256;
            if (e < elems) sdst[e] = lds_val[e];
        }
    }
}

extern "C" void kernel_launch(void* const* d_in, const int* in_sizes, int n_in,
                              void* d_out, int out_size, void* d_ws, size_t ws_size,
                              hipStream_t stream) {
    const float* logits   = (const float*)d_in[0];
    const float4* boxreg4 = (const float4*)d_in[1];
    const float4* prop4   = (const float4*)d_in[2];
    const int*   img_w_p  = (const int*)d_in[3];
    const int*   img_h_p  = (const int*)d_in[4];

    const int N = in_sizes[1] / 4;  // box_regression is (N,4)

    float* out_boxes  = (float*)d_out;
    float* out_scores = out_boxes + (size_t)N * NUM_CLASSES * 4;

    const int bblocks = (N + BROWS - 1) / BROWS;
    boxes_kernel<<<bblocks, 256, 0, stream>>>(
        boxreg4, prop4, img_w_p, img_h_p, out_boxes, N);

    const int sblocks = (N + SROWS - 1) / SROWS;
    scores_kernel<<<sblocks, 256, 0, stream>>>(logits, out_scores, N);
}